// Round 15
// baseline (165.777 us; speedup 1.0000x reference)
//
#include <hip/hip_runtime.h>
#include <hip/hip_bf16.h>

#define N_NODES 50000
#define P_PATHS 200000
#define N_ROWS  250000
#define L_EDGES 6
#define T_LEN   128
#define F_BINS  65
#define EPSF    1e-12f
#define PIF     3.14159265358979323846f
#define COORD_ELEMS ((size_t)2 * (P_PATHS + N_NODES))   // 500000 f32
#define FREQ_BYTES  ((size_t)N_NODES * F_BINS * 8)      // 26,000,000 (16B aligned)
#define KDIM  160      // padded K (fr/fi interleaved 130, zero-padded)
#define KPAD  168      // LDS row stride in halves (bank-conflict pad)
#define ROWS_BLK 64

typedef _Float16 v2h __attribute__((ext_vector_type(2)));
typedef _Float16 v8h __attribute__((ext_vector_type(8)));
typedef float    v4f __attribute__((ext_vector_type(4)));

__device__ __forceinline__ float softplus_(float x) {
    const float e = __expf(-fabsf(x));
    return fmaxf(x, 0.0f) + __logf(1.0f + e);
}

__device__ __forceinline__ float lgamma_pos_(float x) {
    const float ser = 1.000000000190015f
                    + 76.18009172947146f     / (x + 1.0f)
                    - 86.50532032941677f     / (x + 2.0f)
                    + 24.01409824083091f     / (x + 3.0f)
                    - 1.231739572450155f     / (x + 4.0f)
                    + 0.1208650973866179e-2f / (x + 5.0f)
                    - 0.5395239384953e-5f    / (x + 6.0f);
    const float tmp = x + 5.5f;
    return (x + 0.5f) * __logf(tmp) - tmp + __logf(2.5066282746310005f * ser / x);
}

// ---------------- K0: irfft weight matrix W^T[t][kk], fp16, 128x160 ----------------
// x[t] = sum_kk F[kk] * W[kk][t];  kk=2j -> fr_j * cj*cos(2pi j t/128)/128,
// kk=2j+1 -> fi_j * (-cj*sin(...))/128;  cj = 1 for j in {0,64}, else 2.
__global__ void irfa49o_wgen(_Float16* __restrict__ Wt) {
    const int idx = blockIdx.x * 256 + threadIdx.x;
    if (idx >= 128 * KDIM) return;
    const int t  = idx / KDIM;
    const int kk = idx - t * KDIM;
    float val = 0.0f;
    if (kk < 130 && kk != 129) {                 // kk=129 is fi_64 (weight 0)
        const int j = kk >> 1;
        const int m = (j * t) & 127;             // exact integer phase reduction
        const float th = (float)m * (PIF / 64.0f);
        const float cj = (j == 0 || j == 64) ? 1.0f : 2.0f;
        const float tri = (kk & 1) ? -__sinf(th) : __cosf(th);
        val = cj * tri * (1.0f / 128.0f);
    }
    Wt[idx] = (_Float16)val;
}

// ---------------- K1: gamma IRF -> rfft (unchanged from r14) ----------------
__global__ void irfa49n_freq(const float* __restrict__ params, float2* __restrict__ freq) {
    __shared__ float sx[8][T_LEN];
    __shared__ float su[8][64];
    __shared__ float sv[8][64];
    const int tid  = threadIdx.x;
    const int slot = tid >> 5;
    const int tl   = tid & 31;
    const int n    = blockIdx.x * 8 + slot;

    const float a  = softplus_(params[2 * n + 0]) + 1.0f;
    const float b  = softplus_(params[2 * n + 1]) + 0.5f;
    const float lg = lgamma_pos_(a);
    const float lb = __logf(b);
    const float rb = 1.0f / b;
    const float am1 = a - 1.0f;
    const float cst = -lg - a * lb;

    float S = 0.0f;
    #pragma unroll
    for (int j = 0; j < 4; ++j) {
        const float tc = (float)(tl + 32 * j) + 0.5f;
        const float x  = __expf(fmaf(am1, __logf(tc), fmaf(-tc, rb, cst)));
        sx[slot][tl + 32 * j] = x;
        S += x;
    }

    float s0  = S;
    float s64 = (tl & 1) ? -S : S;
    float c32 = ((tl & 3) == 0) ? S : (((tl & 3) == 2) ? -S : 0.0f);
    float s32 = ((tl & 3) == 1) ? S : (((tl & 3) == 3) ? -S : 0.0f);
    #pragma unroll
    for (int m = 16; m; m >>= 1) {
        s0  += __shfl_xor(s0, m);
        s64 += __shfl_xor(s64, m);
        c32 += __shfl_xor(c32, m);
        s32 += __shfl_xor(s32, m);
    }
    __syncthreads();

    {
        const int i1 = tl + 1;
        const float xa = sx[slot][i1], xb = sx[slot][T_LEN - i1];
        su[slot][i1] = xa + xb;
        sv[slot][i1] = xa - xb;
        if (tl < 31) {
            const int i2 = tl + 33;
            const float xc = sx[slot][i2], xd = sx[slot][T_LEN - i2];
            su[slot][i2] = xc + xd;
            sv[slot][i2] = xc - xd;
        }
    }
    __syncthreads();

    if (tl == 0) {
        float2 z;
        z.x = s0;  z.y = 0.0f;              freq[n * F_BINS + 0]  = z;
        z.x = c32; z.y = -s32;              freq[n * F_BINS + 32] = z;
        z.x = s64; z.y = 0.0f;              freq[n * F_BINS + 64] = z;
        return;
    }

    const float x0v  = sx[slot][0];
    const float x64v = sx[slot][64];
    const int   k    = tl;
    const float th   = (float)k * (PIF / 64.0f);
    const float c1 = __cosf(th), s1 = __sinf(th);
    const float c2 = 2.0f * c1 * c1 - 1.0f;
    const float s2 = 2.0f * s1 * c1;
    const float K  = 2.0f * c2;

    float ue1 = 0.0f, ue2 = 0.0f, ve1 = 0.0f, ve2 = 0.0f;
    float uo1 = 0.0f, uo2 = 0.0f, vo1 = 0.0f, vo2 = 0.0f;
    #pragma unroll
    for (int m = 31; m >= 1; --m) {
        const float2 uu = *(const float2*)&su[slot][2 * m];
        const float2 vv = *(const float2*)&sv[slot][2 * m];
        float v0;
        v0 = fmaf(K, ue1, uu.x - ue2); ue2 = ue1; ue1 = v0;
        v0 = fmaf(K, ve1, vv.x - ve2); ve2 = ve1; ve1 = v0;
        v0 = fmaf(K, uo1, uu.y - uo2); uo2 = uo1; uo1 = v0;
        v0 = fmaf(K, vo1, vv.y - vo2); vo2 = vo1; vo1 = v0;
    }
    {
        float v0;
        v0 = fmaf(K, uo1, su[slot][1] - uo2); uo2 = uo1; uo1 = v0;
        v0 = fmaf(K, vo1, sv[slot][1] - vo2); vo2 = vo1; vo1 = v0;
    }

    const float Ec = fmaf(ue1, c2, -ue2);
    const float Es = ve1 * s2;
    const float ReSu = fmaf(-uo2, c2, uo1);
    const float ImSu = uo2 * s2;
    const float Oc   = c1 * ReSu - s1 * ImSu;
    const float ReSv = fmaf(-vo2, c2, vo1);
    const float ImSv = vo2 * s2;
    const float Os   = s1 * ReSv + c1 * ImSv;

    const float base = x0v + ((k & 1) ? -x64v : x64v);
    float2 fk, fr;
    fk.x = base + Ec + Oc;
    fk.y = -(Es + Os);
    fr.x = base + Ec - Oc;
    fr.y = Es - Os;
    freq[n * F_BINS + k]      = fk;
    freq[n * F_BINS + 64 - k] = fr;
}

// ---------------- K2: path product (VALU) + irfft (MFMA fp16 GEMM) ----------------
__global__ __launch_bounds__(256) void irfa49o_paths(const float2* __restrict__ freq,
                                                     const int* __restrict__ edges,
                                                     const _Float16* __restrict__ Wt,
                                                     float* __restrict__ out_agg) {
    __shared__ _Float16 sA[ROWS_BLK][KPAD];
    const int tid   = threadIdx.x;
    const int rbase = blockIdx.x * ROWS_BLK;

    // ---- phase 1: spectral products -> LDS fp16 [row][kk], kk = 2*bin (+1 for imag)
    {
        const int slot = tid >> 5;   // 0..7
        const int tl   = tid & 31;   // bin tl and tl+32
        #pragma unroll
        for (int pass = 0; pass < 8; ++pass) {
            const int rho = pass * 8 + slot;
            const int r   = rbase + rho;
            float p1r = 0.0f, p1i = 0.0f, p2r = 0.0f, p2i = 0.0f, q = 0.0f;
            if (r < P_PATHS) {
                p1r = 1.0f; p2r = 1.0f; q = 1.0f;
                const int eb = r * L_EDGES;
                for (int j = 0; j < L_EDGES; ++j) {
                    const int e = edges[eb + j];
                    const float2 av = freq[e * F_BINS + tl];
                    const float2 bv = freq[e * F_BINS + tl + 32];
                    const float f64 = freq[e * F_BINS + 64].x;
                    float t1 = p1r * av.x - p1i * av.y;
                    p1i      = p1r * av.y + p1i * av.x;
                    p1r = t1;
                    float t2 = p2r * bv.x - p2i * bv.y;
                    p2i      = p2r * bv.y + p2i * bv.x;
                    p2r = t2;
                    q *= f64;
                }
            } else if (r < N_ROWS) {
                const int n = r - P_PATHS;
                const float2 av = freq[n * F_BINS + tl];
                const float2 bv = freq[n * F_BINS + tl + 32];
                p1r = av.x; p1i = av.y;
                p2r = bv.x; p2i = bv.y;
                q = freq[n * F_BINS + 64].x;
            }
            v2h h;
            h[0] = (_Float16)p1r; h[1] = (_Float16)p1i;
            *(v2h*)&sA[rho][2 * tl] = h;                 // kk = 2*tl, 2*tl+1
            h[0] = (_Float16)p2r; h[1] = (_Float16)p2i;
            *(v2h*)&sA[rho][2 * tl + 64] = h;            // kk = 2*(tl+32)
            if (tl == 0) {
                v2h z; z[0] = (_Float16)q; z[1] = (_Float16)0.0f;
                *(v2h*)&sA[rho][128] = z;                // fr64, fi64(=ignored)
            }
            if (tl < 15) {                               // zero-pad kk 130..159
                v2h z; z[0] = (_Float16)0.0f; z[1] = (_Float16)0.0f;
                *(v2h*)&sA[rho][130 + 2 * tl] = z;
            }
        }
    }
    __syncthreads();

    // ---- phase 2: MFMA GEMM  D[64 rows][128 t] = sA[64][160] x W[160][128]
    const int wv    = tid >> 6;         // wave 0..3 -> 16 rows each
    const int lane  = tid & 63;
    const int arow  = wv * 16 + (lane & 15);
    const int kgrp  = (lane >> 4) * 8;
    const int tcol  = lane & 15;

    v4f acc[8];
    #pragma unroll
    for (int nt = 0; nt < 8; ++nt) acc[nt] = (v4f){0.0f, 0.0f, 0.0f, 0.0f};

    #pragma unroll
    for (int kt = 0; kt < 5; ++kt) {
        const int kk = kt * 32 + kgrp;
        const v8h afrag = *(const v8h*)&sA[arow][kk];
        #pragma unroll
        for (int nt = 0; nt < 8; ++nt) {
            const int t = nt * 16 + tcol;
            const v8h bfrag = *(const v8h*)&Wt[t * KDIM + kk];   // L2-hot, 40KB total
            acc[nt] = __builtin_amdgcn_mfma_f32_16x16x32_f16(afrag, bfrag, acc[nt], 0, 0, 0);
        }
    }

    // ---- phase 3: relu -> row-sum -> normalize -> flipped store
    const int rgrp = (lane >> 4) * 4;   // D row = rgrp + reg
    #pragma unroll
    for (int reg = 0; reg < 4; ++reg) {
        float vals[8];
        float vsum = 0.0f;
        #pragma unroll
        for (int nt = 0; nt < 8; ++nt) {
            const float v = fmaxf(acc[nt][reg], 0.0f);
            vals[nt] = v;
            vsum += v;
        }
        vsum += __shfl_xor(vsum, 1);
        vsum += __shfl_xor(vsum, 2);
        vsum += __shfl_xor(vsum, 4);
        vsum += __shfl_xor(vsum, 8);
        const int row = rbase + wv * 16 + rgrp + reg;
        if (row < N_ROWS) {
            const float inv = 1.0f / (vsum + EPSF);
            float* op = out_agg + (size_t)row * T_LEN;
            #pragma unroll
            for (int nt = 0; nt < 8; ++nt) {
                const int t = nt * 16 + tcol;
                op[127 - t] = vals[nt] * inv;            // flip
            }
        }
    }
}

// ---------------- K3: coords as f32 (unchanged) ----------------
__global__ void IRFAggregator_39049842655549_kernel(const int* __restrict__ edges,
                                                    float* __restrict__ out) {
    const int M = P_PATHS + N_NODES;
    const int i = blockIdx.x * blockDim.x + threadIdx.x;
    if (i >= 2 * M) return;
    int v;
    if (i < P_PATHS) {
        v = edges[i * L_EDGES];
    } else if (i < M) {
        v = i - P_PATHS;
    } else {
        const int j = i - M;
        if (j < P_PATHS) v = edges[j * L_EDGES + L_EDGES - 1];
        else             v = j - P_PATHS;
    }
    out[i] = (float)v;
}

extern "C" void kernel_launch(void* const* d_in, const int* in_sizes, int n_in,
                              void* d_out, int out_size, void* d_ws, size_t ws_size,
                              hipStream_t stream) {
    const float* params = (const float*)d_in[0];
    const int*   edges  = (const int*)d_in[1];

    float2*    freq = (float2*)d_ws;                               // 26 MB
    _Float16*  Wt   = (_Float16*)((char*)d_ws + FREQ_BYTES);       // 40 KB, 16B aligned
    float* out      = (float*)d_out;
    float* out_agg  = out + COORD_ELEMS;

    IRFAggregator_39049842655549_kernel<<<(int)((COORD_ELEMS + 255) / 256), 256, 0, stream>>>(edges, out);
    irfa49o_wgen<<<(128 * KDIM + 255) / 256, 256, 0, stream>>>(Wt);
    irfa49n_freq<<<N_NODES / 8, 256, 0, stream>>>(params, freq);
    irfa49o_paths<<<(N_ROWS + ROWS_BLK - 1) / ROWS_BLK, 256, 0, stream>>>(freq, edges, Wt, out_agg);
}

// Round 16
// 131.437 us; speedup vs baseline: 1.2613x; 1.2613x over previous
//
#include <hip/hip_runtime.h>
#include <hip/hip_bf16.h>

#define N_NODES 50000
#define P_PATHS 200000
#define N_ROWS  250000
#define L_EDGES 6
#define T_LEN   128
#define F_BINS  65
#define EPSF    1e-12f
#define PIF     3.14159265358979323846f
#define COORD_ELEMS ((size_t)2 * (P_PATHS + N_NODES))   // 500000 f32
#define FREQ_BYTES  ((size_t)N_NODES * F_BINS * 8)      // ws offset for Wt (kept)
#define KDIM  160      // padded K for GEMM (fr/fi interleaved 130, zero-padded)
#define KPAD  168      // LDS row stride in halves
#define KPADN 136      // fp16 freq-table row stride in halves (272 B/node)
#define ROWS_BLK 64

typedef _Float16 v2h __attribute__((ext_vector_type(2)));
typedef _Float16 v8h __attribute__((ext_vector_type(8)));
typedef float    v4f __attribute__((ext_vector_type(4)));

__device__ __forceinline__ float softplus_(float x) {
    const float e = __expf(-fabsf(x));
    return fmaxf(x, 0.0f) + __logf(1.0f + e);
}

__device__ __forceinline__ float lgamma_pos_(float x) {
    const float ser = 1.000000000190015f
                    + 76.18009172947146f     / (x + 1.0f)
                    - 86.50532032941677f     / (x + 2.0f)
                    + 24.01409824083091f     / (x + 3.0f)
                    - 1.231739572450155f     / (x + 4.0f)
                    + 0.1208650973866179e-2f / (x + 5.0f)
                    - 0.5395239384953e-5f    / (x + 6.0f);
    const float tmp = x + 5.5f;
    return (x + 0.5f) * __logf(tmp) - tmp + __logf(2.5066282746310005f * ser / x);
}

// ---------------- K0: irfft weight matrix W^T[t][kk], fp16, 128x160 (unchanged) ----------------
__global__ void irfa49o_wgen(_Float16* __restrict__ Wt) {
    const int idx = blockIdx.x * 256 + threadIdx.x;
    if (idx >= 128 * KDIM) return;
    const int t  = idx / KDIM;
    const int kk = idx - t * KDIM;
    float val = 0.0f;
    if (kk < 130 && kk != 129) {
        const int j = kk >> 1;
        const int m = (j * t) & 127;
        const float th = (float)m * (PIF / 64.0f);
        const float cj = (j == 0 || j == 64) ? 1.0f : 2.0f;
        const float tri = (kk & 1) ? -__sinf(th) : __cosf(th);
        val = cj * tri * (1.0f / 128.0f);
    }
    Wt[idx] = (_Float16)val;
}

// ---------------- K1: gamma IRF -> rfft -> fp16 interleaved table [node][136] ----------------
__global__ void irfa49p_freq(const float* __restrict__ params, _Float16* __restrict__ freqh) {
    __shared__ float sx[8][T_LEN];
    __shared__ float su[8][64];
    __shared__ float sv[8][64];
    const int tid  = threadIdx.x;
    const int slot = tid >> 5;
    const int tl   = tid & 31;
    const int n    = blockIdx.x * 8 + slot;
    _Float16* fh   = freqh + (size_t)n * KPADN;

    const float a  = softplus_(params[2 * n + 0]) + 1.0f;
    const float b  = softplus_(params[2 * n + 1]) + 0.5f;
    const float lg = lgamma_pos_(a);
    const float lb = __logf(b);
    const float rb = 1.0f / b;
    const float am1 = a - 1.0f;
    const float cst = -lg - a * lb;

    float S = 0.0f;
    #pragma unroll
    for (int j = 0; j < 4; ++j) {
        const float tc = (float)(tl + 32 * j) + 0.5f;
        const float x  = __expf(fmaf(am1, __logf(tc), fmaf(-tc, rb, cst)));
        sx[slot][tl + 32 * j] = x;
        S += x;
    }

    float s0  = S;
    float s64 = (tl & 1) ? -S : S;
    float c32 = ((tl & 3) == 0) ? S : (((tl & 3) == 2) ? -S : 0.0f);
    float s32 = ((tl & 3) == 1) ? S : (((tl & 3) == 3) ? -S : 0.0f);
    #pragma unroll
    for (int m = 16; m; m >>= 1) {
        s0  += __shfl_xor(s0, m);
        s64 += __shfl_xor(s64, m);
        c32 += __shfl_xor(c32, m);
        s32 += __shfl_xor(s32, m);
    }
    __syncthreads();

    {
        const int i1 = tl + 1;
        const float xa = sx[slot][i1], xb = sx[slot][T_LEN - i1];
        su[slot][i1] = xa + xb;
        sv[slot][i1] = xa - xb;
        if (tl < 31) {
            const int i2 = tl + 33;
            const float xc = sx[slot][i2], xd = sx[slot][T_LEN - i2];
            su[slot][i2] = xc + xd;
            sv[slot][i2] = xc - xd;
        }
    }
    __syncthreads();

    if (tl == 0) {
        v2h h;
        h[0] = (_Float16)s0;  h[1] = (_Float16)0.0f;  *(v2h*)(fh + 0)   = h;
        h[0] = (_Float16)c32; h[1] = (_Float16)(-s32); *(v2h*)(fh + 64) = h;
        h[0] = (_Float16)s64; h[1] = (_Float16)0.0f;  *(v2h*)(fh + 128) = h;
        h[0] = (_Float16)0.0f; h[1] = (_Float16)0.0f;
        *(v2h*)(fh + 130) = h; *(v2h*)(fh + 132) = h; *(v2h*)(fh + 134) = h;
        return;
    }

    const float x0v  = sx[slot][0];
    const float x64v = sx[slot][64];
    const int   k    = tl;
    const float th   = (float)k * (PIF / 64.0f);
    const float c1 = __cosf(th), s1 = __sinf(th);
    const float c2 = 2.0f * c1 * c1 - 1.0f;
    const float s2 = 2.0f * s1 * c1;
    const float K  = 2.0f * c2;

    float ue1 = 0.0f, ue2 = 0.0f, ve1 = 0.0f, ve2 = 0.0f;
    float uo1 = 0.0f, uo2 = 0.0f, vo1 = 0.0f, vo2 = 0.0f;
    #pragma unroll
    for (int m = 31; m >= 1; --m) {
        const float2 uu = *(const float2*)&su[slot][2 * m];
        const float2 vv = *(const float2*)&sv[slot][2 * m];
        float v0;
        v0 = fmaf(K, ue1, uu.x - ue2); ue2 = ue1; ue1 = v0;
        v0 = fmaf(K, ve1, vv.x - ve2); ve2 = ve1; ve1 = v0;
        v0 = fmaf(K, uo1, uu.y - uo2); uo2 = uo1; uo1 = v0;
        v0 = fmaf(K, vo1, vv.y - vo2); vo2 = vo1; vo1 = v0;
    }
    {
        float v0;
        v0 = fmaf(K, uo1, su[slot][1] - uo2); uo2 = uo1; uo1 = v0;
        v0 = fmaf(K, vo1, sv[slot][1] - vo2); vo2 = vo1; vo1 = v0;
    }

    const float Ec = fmaf(ue1, c2, -ue2);
    const float Es = ve1 * s2;
    const float ReSu = fmaf(-uo2, c2, uo1);
    const float ImSu = uo2 * s2;
    const float Oc   = c1 * ReSu - s1 * ImSu;
    const float ReSv = fmaf(-vo2, c2, vo1);
    const float ImSv = vo2 * s2;
    const float Os   = s1 * ReSv + c1 * ImSv;

    const float base = x0v + ((k & 1) ? -x64v : x64v);
    v2h h;
    h[0] = (_Float16)(base + Ec + Oc);
    h[1] = (_Float16)(-(Es + Os));
    *(v2h*)(fh + 2 * k) = h;
    h[0] = (_Float16)(base + Ec - Oc);
    h[1] = (_Float16)(Es - Os);
    *(v2h*)(fh + 2 * (64 - k)) = h;
}

// ---------------- K2: path product (fp16 gather) + irfft (MFMA fp16 GEMM) ----------------
__global__ __launch_bounds__(256) void irfa49p_paths(const _Float16* __restrict__ freqh,
                                                     const int* __restrict__ edges,
                                                     const _Float16* __restrict__ Wt,
                                                     float* __restrict__ out_agg) {
    __shared__ _Float16 sA[ROWS_BLK][KPAD];
    const int tid   = threadIdx.x;
    const int rbase = blockIdx.x * ROWS_BLK;

    // ---- phase 1: spectral products -> LDS fp16 [row][kk]
    {
        const int slot = tid >> 5;   // 0..7
        const int tl   = tid & 31;   // bins tl, tl+32
        #pragma unroll
        for (int pass = 0; pass < 8; ++pass) {
            const int rho = pass * 8 + slot;
            const int r   = rbase + rho;
            float p1r = 0.0f, p1i = 0.0f, p2r = 0.0f, p2i = 0.0f, q = 0.0f;
            if (r < P_PATHS) {
                p1r = 1.0f; p2r = 1.0f; q = 1.0f;
                const int eb = r * L_EDGES;
                for (int j = 0; j < L_EDGES; ++j) {
                    const int e = edges[eb + j];
                    const _Float16* fh = freqh + (size_t)e * KPADN;
                    const v2h av = *(const v2h*)(fh + 2 * tl);
                    const v2h bv = *(const v2h*)(fh + 64 + 2 * tl);
                    const float f64 = (float)fh[128];
                    const float ax = (float)av[0], ay = (float)av[1];
                    float t1 = p1r * ax - p1i * ay;
                    p1i      = p1r * ay + p1i * ax;
                    p1r = t1;
                    const float bx = (float)bv[0], by = (float)bv[1];
                    float t2 = p2r * bx - p2i * by;
                    p2i      = p2r * by + p2i * bx;
                    p2r = t2;
                    q *= f64;
                }
            } else if (r < N_ROWS) {
                const int n = r - P_PATHS;
                const _Float16* fh = freqh + (size_t)n * KPADN;
                const v2h av = *(const v2h*)(fh + 2 * tl);
                const v2h bv = *(const v2h*)(fh + 64 + 2 * tl);
                p1r = (float)av[0]; p1i = (float)av[1];
                p2r = (float)bv[0]; p2i = (float)bv[1];
                q = (float)fh[128];
            }
            v2h h;
            h[0] = (_Float16)p1r; h[1] = (_Float16)p1i;
            *(v2h*)&sA[rho][2 * tl] = h;
            h[0] = (_Float16)p2r; h[1] = (_Float16)p2i;
            *(v2h*)&sA[rho][2 * tl + 64] = h;
            if (tl == 0) {
                v2h z; z[0] = (_Float16)q; z[1] = (_Float16)0.0f;
                *(v2h*)&sA[rho][128] = z;
            }
            if (tl < 15) {
                v2h z; z[0] = (_Float16)0.0f; z[1] = (_Float16)0.0f;
                *(v2h*)&sA[rho][130 + 2 * tl] = z;
            }
        }
    }
    __syncthreads();

    // ---- phase 2: MFMA GEMM  D[64 rows][128 t] = sA[64][160] x W[160][128]
    const int wv    = tid >> 6;
    const int lane  = tid & 63;
    const int arow  = wv * 16 + (lane & 15);
    const int kgrp  = (lane >> 4) * 8;
    const int tcol  = lane & 15;

    v4f acc[8];
    #pragma unroll
    for (int nt = 0; nt < 8; ++nt) acc[nt] = (v4f){0.0f, 0.0f, 0.0f, 0.0f};

    #pragma unroll
    for (int kt = 0; kt < 5; ++kt) {
        const int kk = kt * 32 + kgrp;
        const v8h afrag = *(const v8h*)&sA[arow][kk];
        #pragma unroll
        for (int nt = 0; nt < 8; ++nt) {
            const int t = nt * 16 + tcol;
            const v8h bfrag = *(const v8h*)&Wt[t * KDIM + kk];
            acc[nt] = __builtin_amdgcn_mfma_f32_16x16x32_f16(afrag, bfrag, acc[nt], 0, 0, 0);
        }
    }

    // ---- phase 3: relu -> row-sum -> normalize -> flipped store
    const int rgrp = (lane >> 4) * 4;
    #pragma unroll
    for (int reg = 0; reg < 4; ++reg) {
        float vals[8];
        float vsum = 0.0f;
        #pragma unroll
        for (int nt = 0; nt < 8; ++nt) {
            const float v = fmaxf(acc[nt][reg], 0.0f);
            vals[nt] = v;
            vsum += v;
        }
        vsum += __shfl_xor(vsum, 1);
        vsum += __shfl_xor(vsum, 2);
        vsum += __shfl_xor(vsum, 4);
        vsum += __shfl_xor(vsum, 8);
        const int row = rbase + wv * 16 + rgrp + reg;
        if (row < N_ROWS) {
            const float inv = 1.0f / (vsum + EPSF);
            float* op = out_agg + (size_t)row * T_LEN;
            #pragma unroll
            for (int nt = 0; nt < 8; ++nt) {
                const int t = nt * 16 + tcol;
                op[127 - t] = vals[nt] * inv;
            }
        }
    }
}

// ---------------- K3: coords as f32 (unchanged) ----------------
__global__ void IRFAggregator_39049842655549_kernel(const int* __restrict__ edges,
                                                    float* __restrict__ out) {
    const int M = P_PATHS + N_NODES;
    const int i = blockIdx.x * blockDim.x + threadIdx.x;
    if (i >= 2 * M) return;
    int v;
    if (i < P_PATHS) {
        v = edges[i * L_EDGES];
    } else if (i < M) {
        v = i - P_PATHS;
    } else {
        const int j = i - M;
        if (j < P_PATHS) v = edges[j * L_EDGES + L_EDGES - 1];
        else             v = j - P_PATHS;
    }
    out[i] = (float)v;
}

extern "C" void kernel_launch(void* const* d_in, const int* in_sizes, int n_in,
                              void* d_out, int out_size, void* d_ws, size_t ws_size,
                              hipStream_t stream) {
    const float* params = (const float*)d_in[0];
    const int*   edges  = (const int*)d_in[1];

    _Float16* freqh = (_Float16*)d_ws;                          // 50000*136*2B = 13.6 MB
    _Float16* Wt    = (_Float16*)((char*)d_ws + FREQ_BYTES);    // 40 KB @ 26 MB mark
    float* out      = (float*)d_out;
    float* out_agg  = out + COORD_ELEMS;

    IRFAggregator_39049842655549_kernel<<<(int)((COORD_ELEMS + 255) / 256), 256, 0, stream>>>(edges, out);
    irfa49o_wgen<<<(128 * KDIM + 255) / 256, 256, 0, stream>>>(Wt);
    irfa49p_freq<<<N_NODES / 8, 256, 0, stream>>>(params, freqh);
    irfa49p_paths<<<(N_ROWS + ROWS_BLK - 1) / ROWS_BLK, 256, 0, stream>>>(freqh, edges, Wt, out_agg);
}

// Round 17
// 131.000 us; speedup vs baseline: 1.2655x; 1.0033x over previous
//
#include <hip/hip_runtime.h>
#include <hip/hip_bf16.h>

#define N_NODES 50000
#define P_PATHS 200000
#define N_ROWS  250000
#define L_EDGES 6
#define T_LEN   128
#define F_BINS  65
#define EPSF    1e-12f
#define PIF     3.14159265358979323846f
#define COORD_ELEMS ((size_t)2 * (P_PATHS + N_NODES))   // 500000 f32
#define FREQ_BYTES  ((size_t)N_NODES * F_BINS * 8)      // ws offset for Wt
#define KDIM  160      // padded K for GEMM (fr/fi interleaved 130, zero-padded)
#define KPAD  192      // LDS row stride in halves (24 x 16B chunks, XOR-swizzled)
#define KPADN 136      // fp16 freq-table row stride in halves (272 B/node)
#define ROWS_BLK 64

typedef _Float16 v2h __attribute__((ext_vector_type(2)));
typedef _Float16 v8h __attribute__((ext_vector_type(8)));
typedef float    v4f __attribute__((ext_vector_type(4)));

__device__ __forceinline__ int swzA(int row, int h) {
    // XOR 16B-chunk index with row&7: phase-2 column reads spread over all banks
    return (((h >> 3) ^ (row & 7)) << 3) | (h & 7);
}

__device__ __forceinline__ float softplus_(float x) {
    const float e = __expf(-fabsf(x));
    return fmaxf(x, 0.0f) + __logf(1.0f + e);
}

__device__ __forceinline__ float lgamma_pos_(float x) {
    const float ser = 1.000000000190015f
                    + 76.18009172947146f     / (x + 1.0f)
                    - 86.50532032941677f     / (x + 2.0f)
                    + 24.01409824083091f     / (x + 3.0f)
                    - 1.231739572450155f     / (x + 4.0f)
                    + 0.1208650973866179e-2f / (x + 5.0f)
                    - 0.5395239384953e-5f    / (x + 6.0f);
    const float tmp = x + 5.5f;
    return (x + 0.5f) * __logf(tmp) - tmp + __logf(2.5066282746310005f * ser / x);
}

// ---------------- K0: irfft weight matrix W^T[t][kk], fp16, 128x160 (unchanged) ----------------
__global__ void irfa49o_wgen(_Float16* __restrict__ Wt) {
    const int idx = blockIdx.x * 256 + threadIdx.x;
    if (idx >= 128 * KDIM) return;
    const int t  = idx / KDIM;
    const int kk = idx - t * KDIM;
    float val = 0.0f;
    if (kk < 130 && kk != 129) {
        const int j = kk >> 1;
        const int m = (j * t) & 127;
        const float th = (float)m * (PIF / 64.0f);
        const float cj = (j == 0 || j == 64) ? 1.0f : 2.0f;
        const float tri = (kk & 1) ? -__sinf(th) : __cosf(th);
        val = cj * tri * (1.0f / 128.0f);
    }
    Wt[idx] = (_Float16)val;
}

// ---------------- K1: gamma IRF -> rfft -> fp16 interleaved table [node][136] (unchanged) ----------------
__global__ void irfa49p_freq(const float* __restrict__ params, _Float16* __restrict__ freqh) {
    __shared__ float sx[8][T_LEN];
    __shared__ float su[8][64];
    __shared__ float sv[8][64];
    const int tid  = threadIdx.x;
    const int slot = tid >> 5;
    const int tl   = tid & 31;
    const int n    = blockIdx.x * 8 + slot;
    _Float16* fh   = freqh + (size_t)n * KPADN;

    const float a  = softplus_(params[2 * n + 0]) + 1.0f;
    const float b  = softplus_(params[2 * n + 1]) + 0.5f;
    const float lg = lgamma_pos_(a);
    const float lb = __logf(b);
    const float rb = 1.0f / b;
    const float am1 = a - 1.0f;
    const float cst = -lg - a * lb;

    float S = 0.0f;
    #pragma unroll
    for (int j = 0; j < 4; ++j) {
        const float tc = (float)(tl + 32 * j) + 0.5f;
        const float x  = __expf(fmaf(am1, __logf(tc), fmaf(-tc, rb, cst)));
        sx[slot][tl + 32 * j] = x;
        S += x;
    }

    float s0  = S;
    float s64 = (tl & 1) ? -S : S;
    float c32 = ((tl & 3) == 0) ? S : (((tl & 3) == 2) ? -S : 0.0f);
    float s32 = ((tl & 3) == 1) ? S : (((tl & 3) == 3) ? -S : 0.0f);
    #pragma unroll
    for (int m = 16; m; m >>= 1) {
        s0  += __shfl_xor(s0, m);
        s64 += __shfl_xor(s64, m);
        c32 += __shfl_xor(c32, m);
        s32 += __shfl_xor(s32, m);
    }
    __syncthreads();

    {
        const int i1 = tl + 1;
        const float xa = sx[slot][i1], xb = sx[slot][T_LEN - i1];
        su[slot][i1] = xa + xb;
        sv[slot][i1] = xa - xb;
        if (tl < 31) {
            const int i2 = tl + 33;
            const float xc = sx[slot][i2], xd = sx[slot][T_LEN - i2];
            su[slot][i2] = xc + xd;
            sv[slot][i2] = xc - xd;
        }
    }
    __syncthreads();

    if (tl == 0) {
        v2h h;
        h[0] = (_Float16)s0;  h[1] = (_Float16)0.0f;   *(v2h*)(fh + 0)   = h;
        h[0] = (_Float16)c32; h[1] = (_Float16)(-s32); *(v2h*)(fh + 64)  = h;
        h[0] = (_Float16)s64; h[1] = (_Float16)0.0f;   *(v2h*)(fh + 128) = h;
        h[0] = (_Float16)0.0f; h[1] = (_Float16)0.0f;
        *(v2h*)(fh + 130) = h; *(v2h*)(fh + 132) = h; *(v2h*)(fh + 134) = h;
        return;
    }

    const float x0v  = sx[slot][0];
    const float x64v = sx[slot][64];
    const int   k    = tl;
    const float th   = (float)k * (PIF / 64.0f);
    const float c1 = __cosf(th), s1 = __sinf(th);
    const float c2 = 2.0f * c1 * c1 - 1.0f;
    const float s2 = 2.0f * s1 * c1;
    const float K  = 2.0f * c2;

    float ue1 = 0.0f, ue2 = 0.0f, ve1 = 0.0f, ve2 = 0.0f;
    float uo1 = 0.0f, uo2 = 0.0f, vo1 = 0.0f, vo2 = 0.0f;
    #pragma unroll
    for (int m = 31; m >= 1; --m) {
        const float2 uu = *(const float2*)&su[slot][2 * m];
        const float2 vv = *(const float2*)&sv[slot][2 * m];
        float v0;
        v0 = fmaf(K, ue1, uu.x - ue2); ue2 = ue1; ue1 = v0;
        v0 = fmaf(K, ve1, vv.x - ve2); ve2 = ve1; ve1 = v0;
        v0 = fmaf(K, uo1, uu.y - uo2); uo2 = uo1; uo1 = v0;
        v0 = fmaf(K, vo1, vv.y - vo2); vo2 = vo1; vo1 = v0;
    }
    {
        float v0;
        v0 = fmaf(K, uo1, su[slot][1] - uo2); uo2 = uo1; uo1 = v0;
        v0 = fmaf(K, vo1, sv[slot][1] - vo2); vo2 = vo1; vo1 = v0;
    }

    const float Ec = fmaf(ue1, c2, -ue2);
    const float Es = ve1 * s2;
    const float ReSu = fmaf(-uo2, c2, uo1);
    const float ImSu = uo2 * s2;
    const float Oc   = c1 * ReSu - s1 * ImSu;
    const float ReSv = fmaf(-vo2, c2, vo1);
    const float ImSv = vo2 * s2;
    const float Os   = s1 * ReSv + c1 * ImSv;

    const float base = x0v + ((k & 1) ? -x64v : x64v);
    v2h h;
    h[0] = (_Float16)(base + Ec + Oc);
    h[1] = (_Float16)(-(Es + Os));
    *(v2h*)(fh + 2 * k) = h;
    h[0] = (_Float16)(base + Ec - Oc);
    h[1] = (_Float16)(Es - Os);
    *(v2h*)(fh + 2 * (64 - k)) = h;
}

// ---------------- K2: path product (deep-ILP gather) + irfft (MFMA, swizzled LDS) ----------------
__global__ __launch_bounds__(256) void irfa49q_paths(const _Float16* __restrict__ freqh,
                                                     const int* __restrict__ edges,
                                                     const _Float16* __restrict__ Wt,
                                                     float* __restrict__ out_agg) {
    __shared__ _Float16 sA[ROWS_BLK * KPAD];
    const int tid   = threadIdx.x;
    const int rbase = blockIdx.x * ROWS_BLK;

    // ---- phase 1: spectral products -> swizzled LDS fp16 [row][kk]
    {
        const int slot = tid >> 5;   // 0..7
        const int tl   = tid & 31;   // bins tl, tl+32
        #pragma unroll
        for (int pass = 0; pass < 8; ++pass) {
            const int rho = pass * 8 + slot;
            const int r   = rbase + rho;
            float p1r = 0.0f, p1i = 0.0f, p2r = 0.0f, p2i = 0.0f, q = 0.0f;
            if (r < P_PATHS) {
                // issue ALL gather loads up-front (18 independent loads in flight)
                int eidx[L_EDGES];
                const int eb = r * L_EDGES;
                #pragma unroll
                for (int j = 0; j < L_EDGES; ++j) eidx[j] = edges[eb + j];
                v2h av[L_EDGES], bv[L_EDGES];
                _Float16 fq[L_EDGES];
                #pragma unroll
                for (int j = 0; j < L_EDGES; ++j) {
                    const _Float16* fh = freqh + (size_t)eidx[j] * KPADN;
                    av[j] = *(const v2h*)(fh + 2 * tl);
                    bv[j] = *(const v2h*)(fh + 64 + 2 * tl);
                    fq[j] = fh[128];
                }
                p1r = 1.0f; p2r = 1.0f; q = 1.0f;
                #pragma unroll
                for (int j = 0; j < L_EDGES; ++j) {
                    const float ax = (float)av[j][0], ay = (float)av[j][1];
                    float t1 = p1r * ax - p1i * ay;
                    p1i      = p1r * ay + p1i * ax;
                    p1r = t1;
                    const float bx = (float)bv[j][0], by = (float)bv[j][1];
                    float t2 = p2r * bx - p2i * by;
                    p2i      = p2r * by + p2i * bx;
                    p2r = t2;
                    q *= (float)fq[j];
                }
            } else if (r < N_ROWS) {
                const int n = r - P_PATHS;
                const _Float16* fh = freqh + (size_t)n * KPADN;
                const v2h av = *(const v2h*)(fh + 2 * tl);
                const v2h bv = *(const v2h*)(fh + 64 + 2 * tl);
                p1r = (float)av[0]; p1i = (float)av[1];
                p2r = (float)bv[0]; p2i = (float)bv[1];
                q = (float)fh[128];
            }
            _Float16* row = sA + rho * KPAD;
            v2h h;
            h[0] = (_Float16)p1r; h[1] = (_Float16)p1i;
            *(v2h*)&row[swzA(rho, 2 * tl)] = h;
            h[0] = (_Float16)p2r; h[1] = (_Float16)p2i;
            *(v2h*)&row[swzA(rho, 64 + 2 * tl)] = h;
            if (tl == 0) {
                v2h z; z[0] = (_Float16)q; z[1] = (_Float16)0.0f;
                *(v2h*)&row[swzA(rho, 128)] = z;
            }
            if (tl < 31) {                      // zero halves 130..191 (pad chunks)
                v2h z; z[0] = (_Float16)0.0f; z[1] = (_Float16)0.0f;
                *(v2h*)&row[swzA(rho, 130 + 2 * tl)] = z;
            }
        }
    }
    __syncthreads();

    // ---- phase 2: MFMA GEMM  D[64 rows][128 t] = sA[64][160] x W[160][128]
    const int wv    = tid >> 6;
    const int lane  = tid & 63;
    const int arow  = wv * 16 + (lane & 15);
    const int kgrp  = (lane >> 4) * 8;
    const int tcol  = lane & 15;

    v4f acc[8];
    #pragma unroll
    for (int nt = 0; nt < 8; ++nt) acc[nt] = (v4f){0.0f, 0.0f, 0.0f, 0.0f};

    #pragma unroll
    for (int kt = 0; kt < 5; ++kt) {
        const int kk = kt * 32 + kgrp;
        const v8h afrag = *(const v8h*)&sA[arow * KPAD + swzA(arow, kk)];
        #pragma unroll
        for (int nt = 0; nt < 8; ++nt) {
            const int t = nt * 16 + tcol;
            const v8h bfrag = *(const v8h*)&Wt[t * KDIM + kk];
            acc[nt] = __builtin_amdgcn_mfma_f32_16x16x32_f16(afrag, bfrag, acc[nt], 0, 0, 0);
        }
    }

    // ---- phase 3: relu -> row-sum -> normalize -> flipped store
    const int rgrp = (lane >> 4) * 4;
    #pragma unroll
    for (int reg = 0; reg < 4; ++reg) {
        float vals[8];
        float vsum = 0.0f;
        #pragma unroll
        for (int nt = 0; nt < 8; ++nt) {
            const float v = fmaxf(acc[nt][reg], 0.0f);
            vals[nt] = v;
            vsum += v;
        }
        vsum += __shfl_xor(vsum, 1);
        vsum += __shfl_xor(vsum, 2);
        vsum += __shfl_xor(vsum, 4);
        vsum += __shfl_xor(vsum, 8);
        const int row = rbase + wv * 16 + rgrp + reg;
        if (row < N_ROWS) {
            const float inv = 1.0f / (vsum + EPSF);
            float* op = out_agg + (size_t)row * T_LEN;
            #pragma unroll
            for (int nt = 0; nt < 8; ++nt) {
                const int t = nt * 16 + tcol;
                op[127 - t] = vals[nt] * inv;
            }
        }
    }
}

// ---------------- K3: coords as f32 (unchanged) ----------------
__global__ void IRFAggregator_39049842655549_kernel(const int* __restrict__ edges,
                                                    float* __restrict__ out) {
    const int M = P_PATHS + N_NODES;
    const int i = blockIdx.x * blockDim.x + threadIdx.x;
    if (i >= 2 * M) return;
    int v;
    if (i < P_PATHS) {
        v = edges[i * L_EDGES];
    } else if (i < M) {
        v = i - P_PATHS;
    } else {
        const int j = i - M;
        if (j < P_PATHS) v = edges[j * L_EDGES + L_EDGES - 1];
        else             v = j - P_PATHS;
    }
    out[i] = (float)v;
}

extern "C" void kernel_launch(void* const* d_in, const int* in_sizes, int n_in,
                              void* d_out, int out_size, void* d_ws, size_t ws_size,
                              hipStream_t stream) {
    const float* params = (const float*)d_in[0];
    const int*   edges  = (const int*)d_in[1];

    _Float16* freqh = (_Float16*)d_ws;                          // 13.6 MB
    _Float16* Wt    = (_Float16*)((char*)d_ws + FREQ_BYTES);    // 40 KB @ 26 MB mark
    float* out      = (float*)d_out;
    float* out_agg  = out + COORD_ELEMS;

    IRFAggregator_39049842655549_kernel<<<(int)((COORD_ELEMS + 255) / 256), 256, 0, stream>>>(edges, out);
    irfa49o_wgen<<<(128 * KDIM + 255) / 256, 256, 0, stream>>>(Wt);
    irfa49p_freq<<<N_NODES / 8, 256, 0, stream>>>(params, freqh);
    irfa49q_paths<<<(N_ROWS + ROWS_BLK - 1) / ROWS_BLK, 256, 0, stream>>>(freqh, edges, Wt, out_agg);
}